// Round 2
// baseline (87.710 us; speedup 1.0000x reference)
//
#include <hip/hip_runtime.h>

typedef __bf16 bf16_t;
typedef __bf16 bf16x4 __attribute__((ext_vector_type(4)));
typedef __bf16 bf16x8 __attribute__((ext_vector_type(8)));
typedef float  f32x4  __attribute__((ext_vector_type(4)));

#define MFMA16(a, b, c) __builtin_amdgcn_mfma_f32_16x16x32_bf16((a), (b), (c), 0, 0, 0)

// ---------------- LDS layout (bytes) ----------------
// region X [0, 17408):  x tile [64][136] bf16  --(after b5)--> att [64][136] bf16
// per head h in 0..3: base = 17408 + h*14848 (elements from base):
//   q  [64][40] bf16 (2560 el)  } overlaid by p [64][72] bf16 (4608 el) after b4
//   k  [64][40] bf16 (2560 el)  }
//   vT [32][72] bf16 (2304 el)
// total = 17408 + 4*14848 = 76800
#define SMEM_BYTES 76800

// Fragment conventions for v_mfma_f32_16x16x32_bf16, D = A*B (verified r0 pass):
//  A (MxK): lane holds A[lane&15][8*(lane>>4)+i], i=0..7   (row-major MxK read)
//  B (KxN): lane holds B[8*(lane>>4)+i][lane&15]           (row-major NxK read of B^T)
//  D (MxN): lane reg r holds D[4*(lane>>4)+r][lane&15]

__device__ __forceinline__ bf16x8 ld8f(const float* __restrict__ p) {
    float4 f0 = *(const float4*)p;
    float4 f1 = *(const float4*)(p + 4);
    bf16x8 r;
    r[0] = (bf16_t)f0.x; r[1] = (bf16_t)f0.y; r[2] = (bf16_t)f0.z; r[3] = (bf16_t)f0.w;
    r[4] = (bf16_t)f1.x; r[5] = (bf16_t)f1.y; r[6] = (bf16_t)f1.z; r[7] = (bf16_t)f1.w;
    return r;
}

__global__ __launch_bounds__(512, 4) void winattn_kernel(
    const float* __restrict__ xg, const float* __restrict__ maskg,
    const float* __restrict__ qwg, const float* __restrict__ qbg,
    const float* __restrict__ pwg, const float* __restrict__ pbg,
    const int nW, float* __restrict__ outg)
{
    extern __shared__ char smem[];
    bf16_t* xatt = (bf16_t*)smem;   // [64][136] bf16 (x, later att)

    const int b    = blockIdx.x;
    const int tid  = threadIdx.x;
    const int w    = tid >> 6;       // wave 0..7
    const int lane = tid & 63;
    const int g    = lane >> 4;      // lane group 0..3
    const int c0   = lane & 15;

    // ---- phase 0: stage x (49x128 f32 -> bf16 LDS), zero rows 49..63 ----
    {
        const float4* xb = (const float4*)(xg + (long)b * 6272);
        #pragma unroll 4
        for (int i = tid; i < 1568; i += 512) {
            float4 f = xb[i];
            int row = i >> 5;
            int col = (i & 31) << 2;
            bf16x4 h;
            h[0] = (bf16_t)f.x; h[1] = (bf16_t)f.y; h[2] = (bf16_t)f.z; h[3] = (bf16_t)f.w;
            *(bf16x4*)(xatt + row * 136 + col) = h;
        }
        unsigned int* z = (unsigned int*)(xatt + 49 * 136);
        for (int i = tid; i < 1020; i += 512) z[i] = 0u;
    }
    __syncthreads();   // b1

    // ---- phase 1: QKV GEMM, D[o][tok] = W*x^T: A=W rows, B=x^T ----
    {
        const int orow0 = 48 * w;
        float4 bias[3];
        #pragma unroll
        for (int nt = 0; nt < 3; ++nt)
            bias[nt] = *(const float4*)(qbg + orow0 + 16 * nt + 4 * g);

        f32x4 acc[3][4];
        #pragma unroll
        for (int nt = 0; nt < 3; ++nt)
            #pragma unroll
            for (int mt = 0; mt < 4; ++mt) acc[nt][mt] = {0.f, 0.f, 0.f, 0.f};

        #pragma unroll
        for (int ks = 0; ks < 4; ++ks) {
            bf16x8 wfk[3];
            #pragma unroll
            for (int nt = 0; nt < 3; ++nt)
                wfk[nt] = ld8f(qwg + (orow0 + 16 * nt + c0) * 128 + 32 * ks + 8 * g);
            bf16x8 xf[4];
            #pragma unroll
            for (int mt = 0; mt < 4; ++mt)
                xf[mt] = *(const bf16x8*)(xatt + (16 * mt + c0) * 136 + 32 * ks + 8 * g);
            #pragma unroll
            for (int nt = 0; nt < 3; ++nt)
                #pragma unroll
                for (int mt = 0; mt < 4; ++mt)
                    acc[nt][mt] = MFMA16(wfk[nt], xf[mt], acc[nt][mt]);
        }

        // scatter: lane reg r -> o = orow0+16nt+4g+r (consecutive), tok = 16mt+c0
        #pragma unroll
        for (int nt = 0; nt < 3; ++nt) {
            int o0   = orow0 + 16 * nt + 4 * g;
            int part = (orow0 + 16 * nt) >> 7;    // wave-uniform: 0=q 1=k 2=v
            int rem  = o0 & 127;
            int hh   = rem >> 5;
            int dh0  = rem & 31;
            bf16_t* hb = (bf16_t*)(smem + 17408 + hh * 14848);
            #pragma unroll
            for (int mt = 0; mt < 4; ++mt) {
                int tok = 16 * mt + c0;
                bf16x4 t;
                t[0] = (bf16_t)(acc[nt][mt][0] + bias[nt].x);
                t[1] = (bf16_t)(acc[nt][mt][1] + bias[nt].y);
                t[2] = (bf16_t)(acc[nt][mt][2] + bias[nt].z);
                t[3] = (bf16_t)(acc[nt][mt][3] + bias[nt].w);
                if (part == 0) {
                    *(bf16x4*)(hb + tok * 40 + dh0) = t;           // q [tok][dh]
                } else if (part == 1) {
                    *(bf16x4*)(hb + 2560 + tok * 40 + dh0) = t;    // k [tok][dh]
                } else {
                    bf16_t* vt = hb + 5120;                        // vT [dh][tok]
                    vt[(dh0 + 0) * 72 + tok] = t[0];
                    vt[(dh0 + 1) * 72 + tok] = t[1];
                    vt[(dh0 + 2) * 72 + tok] = t[2];
                    vt[(dh0 + 3) * 72 + tok] = t[3];
                }
            }
        }
    }
    __syncthreads();   // b2: q/k/vT visible; x dead (but xatt reused only after b5)

    // ---- phase 2: mask direct from global (L2-hot) + q/k fragment preload ----
    const int h   = w >> 1;    // head
    const int qh2 = w & 1;     // which 32 q-rows
    bf16_t* qls = (bf16_t*)(smem + 17408 + h * 14848);
    bf16_t* kls = qls + 2560;
    bf16_t* vls = qls + 5120;
    bf16_t* pls = qls;         // p overlays q+k after b4

    float mvals[2][16];
    {
        const float* mrow = maskg + (long)(b % nW) * 2401;
        #pragma unroll
        for (int nt = 0; nt < 2; ++nt) {
            int q  = (qh2 * 2 + nt) * 16 + c0;
            int qm = q < 49 ? q : 48;
            const float* mr = mrow + qm * 49;
            #pragma unroll
            for (int mt = 0; mt < 4; ++mt)
                #pragma unroll
                for (int r = 0; r < 4; ++r) {
                    int kv = 16 * mt + 4 * g + r;
                    mvals[nt][mt * 4 + r] = (kv < 49) ? mr[kv] : -1e30f;
                }
        }
    }

    bf16x8 ka[4], qb2[2];
    #pragma unroll
    for (int mt = 0; mt < 4; ++mt)
        ka[mt] = *(const bf16x8*)(kls + (16 * mt + c0) * 40 + 8 * g);
    #pragma unroll
    for (int nt = 0; nt < 2; ++nt)
        qb2[nt] = *(const bf16x8*)(qls + ((qh2 * 2 + nt) * 16 + c0) * 40 + 8 * g);
    __syncthreads();   // b4: all q/k reads done before p writes

    // ---- phase 4: S^T = K*Q^T, softmax over kv (in-register), P -> LDS ----
    {
        const float scale = 0.17677669529663687f;   // 32^-0.5
        #pragma unroll
        for (int nt = 0; nt < 2; ++nt) {
            f32x4 s[4];
            #pragma unroll
            for (int mt = 0; mt < 4; ++mt) s[mt] = {0.f, 0.f, 0.f, 0.f};
            #pragma unroll
            for (int mt = 0; mt < 4; ++mt)
                s[mt] = MFMA16(ka[mt], qb2[nt], s[mt]);   // D[kv][q]

            int q = (qh2 * 2 + nt) * 16 + c0;
            float lg[16];
            float m = -1e30f;
            #pragma unroll
            for (int mt = 0; mt < 4; ++mt)
                #pragma unroll
                for (int r = 0; r < 4; ++r) {
                    float v = s[mt][r] * scale + mvals[nt][mt * 4 + r];
                    lg[mt * 4 + r] = v;
                    m = fmaxf(m, v);
                }
            m = fmaxf(m, __shfl_xor(m, 16));
            m = fmaxf(m, __shfl_xor(m, 32));
            float sum = 0.f;
            #pragma unroll
            for (int i = 0; i < 16; ++i) { float e = __expf(lg[i] - m); lg[i] = e; sum += e; }
            sum += __shfl_xor(sum, 16);
            sum += __shfl_xor(sum, 32);
            float inv = 1.f / sum;
            #pragma unroll
            for (int mt = 0; mt < 4; ++mt) {
                bf16x4 t;
                t[0] = (bf16_t)(lg[mt * 4 + 0] * inv);
                t[1] = (bf16_t)(lg[mt * 4 + 1] * inv);
                t[2] = (bf16_t)(lg[mt * 4 + 2] * inv);
                t[3] = (bf16_t)(lg[mt * 4 + 3] * inv);
                *(bf16x4*)(pls + q * 72 + 16 * mt + 4 * g) = t;   // p [q][kv]
            }
        }
    }
    __syncthreads();   // b5: p visible; x region dead -> att

    // ---- phase 5: out^T = V^T * P^T, write att[tok][c]; hoist proj weights ----
    bf16x8 pwf[4];
    float4 pbias;
    {
        #pragma unroll
        for (int ks = 0; ks < 4; ++ks)
            pwf[ks] = ld8f(pwg + (16 * w + c0) * 128 + 32 * ks + 8 * g);
        pbias = *(const float4*)(pbg + 16 * w + 4 * g);

        f32x4 oo[2][2];
        #pragma unroll
        for (int mt = 0; mt < 2; ++mt)
            #pragma unroll
            for (int nt = 0; nt < 2; ++nt) oo[mt][nt] = {0.f, 0.f, 0.f, 0.f};
        #pragma unroll
        for (int ks = 0; ks < 2; ++ks) {
            bf16x8 va[2], pf[2];
            #pragma unroll
            for (int mt = 0; mt < 2; ++mt)
                va[mt] = *(const bf16x8*)(vls + (16 * mt + c0) * 72 + 32 * ks + 8 * g);
            #pragma unroll
            for (int nt = 0; nt < 2; ++nt)
                pf[nt] = *(const bf16x8*)(pls + ((qh2 * 2 + nt) * 16 + c0) * 72 + 32 * ks + 8 * g);
            #pragma unroll
            for (int mt = 0; mt < 2; ++mt)
                #pragma unroll
                for (int nt = 0; nt < 2; ++nt)
                    oo[mt][nt] = MFMA16(va[mt], pf[nt], oo[mt][nt]);  // D[dh][q]
        }
        #pragma unroll
        for (int nt = 0; nt < 2; ++nt) {
            int q = (qh2 * 2 + nt) * 16 + c0;
            #pragma unroll
            for (int mt = 0; mt < 2; ++mt) {
                bf16x4 t;
                t[0] = (bf16_t)oo[mt][nt][0];
                t[1] = (bf16_t)oo[mt][nt][1];
                t[2] = (bf16_t)oo[mt][nt][2];
                t[3] = (bf16_t)oo[mt][nt][3];
                *(bf16x4*)(xatt + q * 136 + h * 32 + 16 * mt + 4 * g) = t;
            }
        }
    }
    __syncthreads();   // b6: att visible

    // ---- phase 6: proj GEMM, D[col][tok] = Wp*att^T; float4 stores ----
    {
        f32x4 acc[4];
        #pragma unroll
        for (int mt = 0; mt < 4; ++mt) acc[mt] = {0.f, 0.f, 0.f, 0.f};
        #pragma unroll
        for (int ks = 0; ks < 4; ++ks) {
            bf16x8 af[4];
            #pragma unroll
            for (int mt = 0; mt < 4; ++mt)
                af[mt] = *(const bf16x8*)(xatt + (16 * mt + c0) * 136 + 32 * ks + 8 * g);
            #pragma unroll
            for (int mt = 0; mt < 4; ++mt)
                acc[mt] = MFMA16(pwf[ks], af[mt], acc[mt]);   // D[col][tok]
        }
        float* ob = outg + (long)b * 6272;
        #pragma unroll
        for (int mt = 0; mt < 4; ++mt) {
            int tok = 16 * mt + c0;
            if (tok < 49) {
                float4 t;
                t.x = acc[mt][0] + pbias.x;
                t.y = acc[mt][1] + pbias.y;
                t.z = acc[mt][2] + pbias.z;
                t.w = acc[mt][3] + pbias.w;
                *(float4*)(ob + tok * 128 + 16 * w + 4 * g) = t;
            }
        }
    }
}

extern "C" void kernel_launch(void* const* d_in, const int* in_sizes, int n_in,
                              void* d_out, int out_size, void* d_ws, size_t ws_size,
                              hipStream_t stream) {
    const float* xg  = (const float*)d_in[0];
    const float* mg  = (const float*)d_in[1];
    const float* qwg = (const float*)d_in[2];
    const float* qbg = (const float*)d_in[3];
    const float* pwg = (const float*)d_in[4];
    const float* pbg = (const float*)d_in[5];
    float* outg = (float*)d_out;

    const int B  = in_sizes[0] / (49 * 128);   // 2048
    const int nW = in_sizes[1] / (49 * 49);    // 64

    (void)hipFuncSetAttribute((const void*)winattn_kernel,
                              hipFuncAttributeMaxDynamicSharedMemorySize, SMEM_BYTES);

    winattn_kernel<<<B, 512, SMEM_BYTES, stream>>>(
        xg, mg, qwg, qbg, pwg, pbg, nW, outg);
}

// Round 3
// 64.553 us; speedup vs baseline: 1.3587x; 1.3587x over previous
//
#include <hip/hip_runtime.h>

typedef __bf16 bf16_t;
typedef __bf16 bf16x2 __attribute__((ext_vector_type(2)));
typedef __bf16 bf16x4 __attribute__((ext_vector_type(4)));
typedef __bf16 bf16x8 __attribute__((ext_vector_type(8)));
typedef float  f32x4  __attribute__((ext_vector_type(4)));
typedef float  f32x4u __attribute__((ext_vector_type(4), aligned(4)));  // unaligned-ok float4
typedef unsigned int u32;

#define MFMA16(a, b, c) __builtin_amdgcn_mfma_f32_16x16x32_bf16((a), (b), (c), 0, 0, 0)

// ---------------- LDS layout ----------------
// region X [0, 17408):  x tile [64][136] bf16  --(after b2, per-wave)--> att [64][136] bf16
// per head h in 0..3: byte base = 17408 + h*14848 (element offsets from base):
//   q  [64][40] bf16 (2560 el)   k at +2560 (2560 el)   vT [32][72] at +5120 (2304 el)
// total = 17408 + 4*14848 = 76800
#define SMEM_BYTES 76800

// Fragment conventions for v_mfma_f32_16x16x32_bf16, D = A*B (verified r0/r1 pass):
//  A (MxK): lane holds A[lane&15][8*(lane>>4)+i], i=0..7   (row-major MxK read)
//  B (KxN): lane holds B[8*(lane>>4)+i][lane&15]           (row-major read of B^T)
//  D (MxN): lane reg r holds D[4*(lane>>4)+r][lane&15]

union W8 { u32 u[4]; bf16x8 v; };

__device__ __forceinline__ u32 pack2(float a, float b) {
    union { bf16x2 h; u32 u; } c;
    c.h[0] = (bf16_t)a; c.h[1] = (bf16_t)b;
    return c.u;
}

__global__ void wconv_kernel(const float* __restrict__ qw, const float* __restrict__ pw,
                             bf16_t* __restrict__ o) {
    int i = (blockIdx.x * 256 + threadIdx.x) * 4;   // 64*256*4 = 65536
    const float* src = (i < 49152) ? (qw + i) : (pw + (i - 49152));
    float4 f = *(const float4*)src;
    bf16x4 h;
    h[0] = (bf16_t)f.x; h[1] = (bf16_t)f.y; h[2] = (bf16_t)f.z; h[3] = (bf16_t)f.w;
    *(bf16x4*)(o + i) = h;
}

__device__ __forceinline__ bf16x8 ldw(const float* __restrict__ wf,
                                      const bf16_t* __restrict__ wb,
                                      int use_b, int idx) {
    if (use_b) {
        return *(const bf16x8*)(wb + idx);
    } else {
        float4 f0 = *(const float4*)(wf + idx);
        float4 f1 = *(const float4*)(wf + idx + 4);
        bf16x8 r;
        r[0] = (bf16_t)f0.x; r[1] = (bf16_t)f0.y; r[2] = (bf16_t)f0.z; r[3] = (bf16_t)f0.w;
        r[4] = (bf16_t)f1.x; r[5] = (bf16_t)f1.y; r[6] = (bf16_t)f1.z; r[7] = (bf16_t)f1.w;
        return r;
    }
}

__global__ __launch_bounds__(512, 4) void winattn_kernel(
    const float* __restrict__ xg, const float* __restrict__ maskg,
    const float* __restrict__ qwg, const float* __restrict__ qbg,
    const float* __restrict__ pwg, const float* __restrict__ pbg,
    const bf16_t* __restrict__ wqb, const bf16_t* __restrict__ wpb,
    const int use_wbf, const int nW, float* __restrict__ outg)
{
    extern __shared__ char smem[];
    bf16_t* xatt = (bf16_t*)smem;   // [64][136] bf16 (x, later att)

    const int b    = blockIdx.x;
    const int tid  = threadIdx.x;
    const int w    = tid >> 6;       // wave 0..7
    const int lane = tid & 63;
    const int g    = lane >> 4;      // lane group 0..3
    const int c0   = lane & 15;

    // ---- phase 0: stage x (49x128 f32 -> bf16 LDS), zero rows 49..63 ----
    {
        const float4* xb = (const float4*)(xg + (long)b * 6272);
        #pragma unroll 4
        for (int i = tid; i < 1568; i += 512) {
            float4 f = xb[i];
            int row = i >> 5;
            int col = (i & 31) << 2;
            bf16x4 hq;
            hq[0] = (bf16_t)f.x; hq[1] = (bf16_t)f.y; hq[2] = (bf16_t)f.z; hq[3] = (bf16_t)f.w;
            *(bf16x4*)(xatt + row * 136 + col) = hq;
        }
        unsigned int* z = (unsigned int*)(xatt + 49 * 136);
        for (int i = tid; i < 1020; i += 512) z[i] = 0u;
    }
    __syncthreads();   // b1

    // ---- phase 1: QKV GEMM ----
    // q/k: each wave owns 32 outputs o = 32w + [0,32): D[o][tok] = W*x^T  (A=W, B=x^T)
    // v:   each wave owns 16 outputs o = 256+16w+[0,16): D[tok][o] = x*Wv^T (A=x, B=Wv^T)
    {
        const int oqk = 32 * w;                 // 0..224: w<4 -> q, w>=4 -> k
        float4 biasqk[2];
        #pragma unroll
        for (int nt = 0; nt < 2; ++nt)
            biasqk[nt] = *(const float4*)(qbg + oqk + 16 * nt + 4 * g);
        float biasv = qbg[256 + 16 * w + c0];
        const float scale = 0.17677669529663687f;   // 32^-0.5, folded into q
        const float qmul  = (w < 4) ? scale : 1.0f;

        f32x4 aqk[2][4], av[4];
        #pragma unroll
        for (int nt = 0; nt < 2; ++nt)
            #pragma unroll
            for (int mt = 0; mt < 4; ++mt) aqk[nt][mt] = {0.f, 0.f, 0.f, 0.f};
        #pragma unroll
        for (int mt = 0; mt < 4; ++mt) av[mt] = {0.f, 0.f, 0.f, 0.f};

        #pragma unroll
        for (int ks = 0; ks < 4; ++ks) {
            bf16x8 wqk[2], wv;
            #pragma unroll
            for (int nt = 0; nt < 2; ++nt)
                wqk[nt] = ldw(qwg, wqb, use_wbf, (oqk + 16 * nt + c0) * 128 + 32 * ks + 8 * g);
            wv = ldw(qwg, wqb, use_wbf, (256 + 16 * w + c0) * 128 + 32 * ks + 8 * g);
            bf16x8 xf[4];
            #pragma unroll
            for (int mt = 0; mt < 4; ++mt)
                xf[mt] = *(const bf16x8*)(xatt + (16 * mt + c0) * 136 + 32 * ks + 8 * g);
            #pragma unroll
            for (int nt = 0; nt < 2; ++nt)
                #pragma unroll
                for (int mt = 0; mt < 4; ++mt)
                    aqk[nt][mt] = MFMA16(wqk[nt], xf[mt], aqk[nt][mt]);   // D[o][tok]
            #pragma unroll
            for (int mt = 0; mt < 4; ++mt)
                av[mt] = MFMA16(xf[mt], wv, av[mt]);                      // D[tok][o]
        }

        // scatter q/k: reg r -> o = oqk+16nt+4g+r (consecutive dh), tok = 16mt+c0
        #pragma unroll
        for (int nt = 0; nt < 2; ++nt) {
            int oh  = (oqk + 16 * nt) & 127;
            int hh  = oh >> 5;
            int dh0 = 16 * nt /* == oh&31 */ + 4 * g;
            bf16_t* base = (bf16_t*)(smem + 17408 + hh * 14848) + (w < 4 ? 0 : 2560);
            #pragma unroll
            for (int mt = 0; mt < 4; ++mt) {
                int tok = 16 * mt + c0;
                bf16x4 t;
                t[0] = (bf16_t)((aqk[nt][mt][0] + biasqk[nt].x) * qmul);
                t[1] = (bf16_t)((aqk[nt][mt][1] + biasqk[nt].y) * qmul);
                t[2] = (bf16_t)((aqk[nt][mt][2] + biasqk[nt].z) * qmul);
                t[3] = (bf16_t)((aqk[nt][mt][3] + biasqk[nt].w) * qmul);
                *(bf16x4*)(base + tok * 40 + dh0) = t;
            }
        }
        // scatter v: reg r -> tok = 16mt+4g+r (consecutive), dh = 16(w&1)+c0
        {
            int dhv = 16 * (w & 1) + c0;
            bf16_t* vt = (bf16_t*)(smem + 17408 + (w >> 1) * 14848) + 5120;
            #pragma unroll
            for (int mt = 0; mt < 4; ++mt) {
                bf16x4 t;
                t[0] = (bf16_t)(av[mt][0] + biasv);
                t[1] = (bf16_t)(av[mt][1] + biasv);
                t[2] = (bf16_t)(av[mt][2] + biasv);
                t[3] = (bf16_t)(av[mt][3] + biasv);
                *(bf16x4*)(vt + dhv * 72 + 16 * mt + 4 * g) = t;   // vT[dh][tok]
            }
        }
    }
    __syncthreads();   // b2: q/k/vT ready; x dead; NO MORE BARRIERS until proj

    // ---- attention phase (per-wave independent): head h, q-half qh2 ----
    const int h   = w >> 1;
    const int qh2 = w & 1;
    bf16_t* qls = (bf16_t*)(smem + 17408 + h * 14848);
    bf16_t* kls = qls + 2560;
    bf16_t* vls = qls + 5120;

    // prefetch proj weights + bias (needed after b3; hide L2 latency here)
    bf16x8 pwf[4];
    #pragma unroll
    for (int ks = 0; ks < 4; ++ks)
        pwf[ks] = ldw(pwg, wpb, use_wbf, (16 * w + c0) * 128 + 32 * ks + 8 * g);
    float4 pbias4 = *(const float4*)(pbg + 16 * w + 4 * g);

    // mask loads (vectorized; rows L2-hot)
    float mv[2][16];
    {
        const float* mrow = maskg + (long)(b % nW) * 2401;
        #pragma unroll
        for (int nt = 0; nt < 2; ++nt) {
            int q  = (qh2 * 2 + nt) * 16 + c0;
            int qm = q < 49 ? q : 48;
            const float* mr = mrow + qm * 49;
            f32x4u m0 = *(const f32x4u*)(mr + 4 * g);
            f32x4u m1 = *(const f32x4u*)(mr + 16 + 4 * g);
            f32x4u m2 = *(const f32x4u*)(mr + 32 + 4 * g);
            float m48 = mr[48];
            #pragma unroll
            for (int r = 0; r < 4; ++r) {
                mv[nt][0 + r] = m0[r];
                mv[nt][4 + r] = m1[r];
                mv[nt][8 + r] = m2[r];
            }
            mv[nt][12] = (g == 0) ? m48 : -1e30f;
            mv[nt][13] = -1e30f; mv[nt][14] = -1e30f; mv[nt][15] = -1e30f;
        }
    }

    // q/k fragments
    bf16x8 ka[4], qb2[2];
    #pragma unroll
    for (int mt = 0; mt < 4; ++mt)
        ka[mt] = *(const bf16x8*)(kls + (16 * mt + c0) * 40 + 8 * g);
    #pragma unroll
    for (int nt = 0; nt < 2; ++nt)
        qb2[nt] = *(const bf16x8*)(qls + ((qh2 * 2 + nt) * 16 + c0) * 40 + 8 * g);

    // S^T = K*Qs^T -> per-q-row softmax (in-register) -> shuffle-redistribute P
    bf16x8 pa[2][2];   // PV A-fragments [nt][ks]
    const bool gl = (g & 1) != 0, gh = (g & 2) != 0;
    #pragma unroll
    for (int nt = 0; nt < 2; ++nt) {
        f32x4 s[4];
        #pragma unroll
        for (int mt = 0; mt < 4; ++mt) s[mt] = {0.f, 0.f, 0.f, 0.f};
        #pragma unroll
        for (int mt = 0; mt < 4; ++mt)
            s[mt] = MFMA16(ka[mt], qb2[nt], s[mt]);   // D[kv][q], kv=16mt+4g+r, q col=c0

        float lg[16];
        float m = -1e30f;
        #pragma unroll
        for (int mt = 0; mt < 4; ++mt)
            #pragma unroll
            for (int r = 0; r < 4; ++r) {
                float v = s[mt][r] + mv[nt][mt * 4 + r];   // scale pre-folded into q
                lg[mt * 4 + r] = v;
                m = fmaxf(m, v);
            }
        m = fmaxf(m, __shfl_xor(m, 16));
        m = fmaxf(m, __shfl_xor(m, 32));
        float sum = 0.f;
        #pragma unroll
        for (int i = 0; i < 16; ++i) { float e = __expf(lg[i] - m); lg[i] = e; sum += e; }
        sum += __shfl_xor(sum, 16);
        sum += __shfl_xor(sum, 32);
        float inv = 1.f / sum;

        // pack P[q][kv] into bf16x2 words: w[j], j=2mt+(r>>1), elem=r&1
        u32 wd[8];
        #pragma unroll
        for (int j = 0; j < 8; ++j) {
            int mt = j >> 1, rb = (j & 1) * 2;
            wd[j] = pack2(lg[mt * 4 + rb] * inv, lg[mt * 4 + rb + 1] * inv);
        }
        // redistribute within c0-column (4 lanes share same q row):
        // dest lane g needs kv=32ks+8g+i from src g'=2(g&1)+(i>>2), word j=4ks+2(g>>1)+((i&3)>>1)
        u32 X[8], Y[8], Z[8];
        #pragma unroll
        for (int j = 0; j < 8; ++j) X[j] = __shfl_xor(wd[j], 16);
        #pragma unroll
        for (int j = 0; j < 8; ++j) Y[j] = __shfl_xor(wd[j], 32);
        #pragma unroll
        for (int j = 0; j < 8; ++j) Z[j] = __shfl_xor(X[j], 32);
        #pragma unroll
        for (int ks = 0; ks < 2; ++ks) {
            W8 u;
            #pragma unroll
            for (int t = 0; t < 4; ++t) {
                int j0 = 4 * ks + (t & 1);
                int j1 = j0 + 2;
                u32 lo, hi;
                if (t < 2) { lo = gl ? Z[j0] : wd[j0]; hi = gl ? X[j1] : Y[j1]; }
                else       { lo = gl ? Y[j0] : X[j0];  hi = gl ? wd[j1] : Z[j1]; }
                u.u[t] = gh ? hi : lo;
            }
            pa[nt][ks] = u.v;
        }
    }

    // ---- PV: out = P*V (A=P regs, B=vT), write att[tok][c] ----
    {
        f32x4 o2[2][2];
        #pragma unroll
        for (int nt = 0; nt < 2; ++nt)
            #pragma unroll
            for (int dt = 0; dt < 2; ++dt) o2[nt][dt] = {0.f, 0.f, 0.f, 0.f};
        #pragma unroll
        for (int ks = 0; ks < 2; ++ks) {
            bf16x8 vf[2];
            #pragma unroll
            for (int dt = 0; dt < 2; ++dt)
                vf[dt] = *(const bf16x8*)(vls + (16 * dt + c0) * 72 + 32 * ks + 8 * g);
            #pragma unroll
            for (int nt = 0; nt < 2; ++nt)
                #pragma unroll
                for (int dt = 0; dt < 2; ++dt)
                    o2[nt][dt] = MFMA16(pa[nt][ks], vf[dt], o2[nt][dt]);  // D[q][dh]
        }
        #pragma unroll
        for (int nt = 0; nt < 2; ++nt)
            #pragma unroll
            for (int dt = 0; dt < 2; ++dt)
                #pragma unroll
                for (int r = 0; r < 4; ++r) {
                    int q = (qh2 * 2 + nt) * 16 + 4 * g + r;
                    xatt[q * 136 + 32 * h + 16 * dt + c0] = (bf16_t)o2[nt][dt][r];
                }
    }
    __syncthreads();   // b3: att complete

    // ---- proj GEMM: D[col][tok] = Wp*att^T; float4 stores ----
    {
        f32x4 acc[4];
        #pragma unroll
        for (int mt = 0; mt < 4; ++mt) acc[mt] = {0.f, 0.f, 0.f, 0.f};
        #pragma unroll
        for (int ks = 0; ks < 4; ++ks) {
            bf16x8 af[4];
            #pragma unroll
            for (int mt = 0; mt < 4; ++mt)
                af[mt] = *(const bf16x8*)(xatt + (16 * mt + c0) * 136 + 32 * ks + 8 * g);
            #pragma unroll
            for (int mt = 0; mt < 4; ++mt)
                acc[mt] = MFMA16(pwf[ks], af[mt], acc[mt]);   // D[col][tok]
        }
        float* ob = outg + (long)b * 6272;
        #pragma unroll
        for (int mt = 0; mt < 4; ++mt) {
            int tok = 16 * mt + c0;
            if (tok < 49) {
                float4 t;
                t.x = acc[mt][0] + pbias4.x;
                t.y = acc[mt][1] + pbias4.y;
                t.z = acc[mt][2] + pbias4.z;
                t.w = acc[mt][3] + pbias4.w;
                *(float4*)(ob + tok * 128 + 16 * w + 4 * g) = t;
            }
        }
    }
}

extern "C" void kernel_launch(void* const* d_in, const int* in_sizes, int n_in,
                              void* d_out, int out_size, void* d_ws, size_t ws_size,
                              hipStream_t stream) {
    const float* xg  = (const float*)d_in[0];
    const float* mg  = (const float*)d_in[1];
    const float* qwg = (const float*)d_in[2];
    const float* qbg = (const float*)d_in[3];
    const float* pwg = (const float*)d_in[4];
    const float* pbg = (const float*)d_in[5];
    float* outg = (float*)d_out;

    const int B  = in_sizes[0] / (49 * 128);   // 2048
    const int nW = in_sizes[1] / (49 * 49);    // 64

    int use_wbf = (d_ws != nullptr && ws_size >= 131072) ? 1 : 0;
    bf16_t* wqb = (bf16_t*)d_ws;
    bf16_t* wpb = use_wbf ? (wqb + 49152) : nullptr;
    if (use_wbf)
        wconv_kernel<<<64, 256, 0, stream>>>(qwg, pwg, wqb);

    (void)hipFuncSetAttribute((const void*)winattn_kernel,
                              hipFuncAttributeMaxDynamicSharedMemorySize, SMEM_BYTES);

    winattn_kernel<<<B, 512, SMEM_BYTES, stream>>>(
        xg, mg, qwg, qbg, pwg, pbg, wqb, use_wbf ? wpb : wqb, use_wbf, nW, outg);
}